// Round 11
// baseline (87.636 us; speedup 1.0000x reference)
//
#include <hip/hip_runtime.h>

// WiredRNN one step. Coarse-then-fine CSR build (two-level radix by dst):
//   K0: transpose states->bf16 (N,32)  ||  coarse hist (R=98 ranges of 512)
//   K1: tiny scan of 98 range counts -> bases + cursors
//   K2: partition edges into range-grouped staging via per-block LDS hist +
//       one global atomicAdd per (block,range) reservation (exact, ~50K atomics)
//   K3: one block per range: LDS hist 512 bins + LDS scan + place edata,
//       write offsets[node] (absolute). No pcounts, no global scan, no
//       strided 64B-line cursor traffic (round-10 diagnosis).
//   K4: agg (wave/node, bf16 paired-batch gather) + tanh + x-clamp + fused
//       output transpose + y slice.
// inputs: 0:x(B,512) 1:states(B,N) 2:weight(E) 3:bias(N) 4:response(N)
//         5:edge_src(E int32) 6:edge_dst(E int32)
// out: y(B,256) then new_states(B,N), f32, concatenated flat.

#define BATCH 32
#define N_IN 512
#define N_OUT 256
#define RB_LOG 9
#define RB (1 << RB_LOG)   // 512 nodes per range
#define MAXR 128           // max ranges supported by K1/K2 LDS

static __device__ __forceinline__ unsigned short f2bf(float f) {
    unsigned u = __float_as_uint(f);
    unsigned r = (u + 0x7fffu + ((u >> 16) & 1u)) >> 16;   // RNE
    return (unsigned short)r;
}

// ---- K0: fused {transpose (B,N)->(N,32) bf16} + {coarse hist} ----
__global__ __launch_bounds__(1024)
void k0_kernel(const float* __restrict__ s, unsigned short* __restrict__ sTb,
               int N, int tgrid,
               const int* __restrict__ edge_dst, int* __restrict__ ccounts,
               int R, int E, int hchunk) {
    __shared__ int shbuf[1056];          // transpose tile (32*33 f32) / hist[128]
    if ((int)blockIdx.x < tgrid) {
        float* tile = (float*)shbuf;
        int tx = threadIdx.x & 31;
        int ty = threadIdx.x >> 5;       // 0..31
        int n0 = blockIdx.x * 32;
        int n = n0 + tx;
        tile[ty * 33 + tx] = (n < N) ? s[(size_t)ty * N + n] : 0.f;  // ty=b
        __syncthreads();
        int nn = n0 + ty;
        if (nn < N) sTb[(size_t)nn * 32 + tx] = f2bf(tile[tx * 33 + ty]);
        return;
    }
    int hb = blockIdx.x - tgrid;
    for (int i = threadIdx.x; i < MAXR; i += 1024) shbuf[i] = 0;
    __syncthreads();
    int e0 = hb * hchunk, e1 = min(e0 + hchunk, E);
    for (int e = e0 + (int)threadIdx.x * 4; e < e1; e += 1024 * 4) {
        if (e + 3 < e1) {
            int4 d4 = *reinterpret_cast<const int4*>(edge_dst + e);
            int dd[4] = {d4.x, d4.y, d4.z, d4.w};
#pragma unroll
            for (int j = 0; j < 4; ++j)
                if (dd[j] >= N_IN) atomicAdd(&shbuf[dd[j] >> RB_LOG], 1);
        } else {
            for (int j = 0; j < 4 && e + j < e1; ++j) {
                int d = edge_dst[e + j];
                if (d >= N_IN) atomicAdd(&shbuf[d >> RB_LOG], 1);
            }
        }
    }
    __syncthreads();
    for (int i = threadIdx.x; i < R; i += 1024)
        if (shbuf[i]) atomicAdd(&ccounts[i], shbuf[i]);
}

// ---- K1: exclusive scan of R<=128 range counts -> bases, cursors ----
__global__ void k1_kernel(const int* __restrict__ ccounts,
                          int* __restrict__ bases, int* __restrict__ cursors,
                          int R) {
    __shared__ int sh[MAXR];
    int tid = threadIdx.x;
    int v = (tid < R) ? ccounts[tid] : 0;
    sh[tid] = v;
    __syncthreads();
    for (int off = 1; off < MAXR; off <<= 1) {
        int t = (tid >= off) ? sh[tid - off] : 0;
        __syncthreads();
        sh[tid] += t;
        __syncthreads();
    }
    int excl = sh[tid] - v;
    if (tid < R) { bases[tid] = excl; cursors[tid] = excl; }
    if (tid == R - 1) bases[R] = sh[tid];
}

// ---- K2: partition edges into range-grouped staging ----
__global__ __launch_bounds__(1024)
void k2_kernel(const int* __restrict__ edge_src,
               const int* __restrict__ edge_dst,
               const float* __restrict__ weight,
               int* __restrict__ cursors,
               int2* __restrict__ staging, int E, int R, int pchunk) {
    __shared__ int h[MAXR];
    __shared__ int lcur[MAXR];
    for (int i = threadIdx.x; i < MAXR; i += 1024) h[i] = 0;
    __syncthreads();
    int e0 = blockIdx.x * pchunk, e1 = min(e0 + pchunk, E);
    // pass A: local counts
    for (int e = e0 + (int)threadIdx.x * 4; e < e1; e += 1024 * 4) {
        if (e + 3 < e1) {
            int4 d4 = *reinterpret_cast<const int4*>(edge_dst + e);
            int dd[4] = {d4.x, d4.y, d4.z, d4.w};
#pragma unroll
            for (int j = 0; j < 4; ++j)
                if (dd[j] >= N_IN) atomicAdd(&h[dd[j] >> RB_LOG], 1);
        } else {
            for (int j = 0; j < 4 && e + j < e1; ++j) {
                int d = edge_dst[e + j];
                if (d >= N_IN) atomicAdd(&h[d >> RB_LOG], 1);
            }
        }
    }
    __syncthreads();
    // reserve exact contiguous slices (one global atomic per non-empty range)
    for (int i = threadIdx.x; i < R; i += 1024) {
        int c = h[i];
        lcur[i] = c ? atomicAdd(&cursors[i], c) : 0;
    }
    __syncthreads();
    // pass B: place packed records {(dlow<<16)|src, w}
    for (int e = e0 + (int)threadIdx.x * 4; e < e1; e += 1024 * 4) {
        if (e + 3 < e1) {
            int4 d4 = *reinterpret_cast<const int4*>(edge_dst + e);
            int4 s4 = *reinterpret_cast<const int4*>(edge_src + e);
            float4 w4 = *reinterpret_cast<const float4*>(weight + e);
            int dd[4] = {d4.x, d4.y, d4.z, d4.w};
            int ss[4] = {s4.x, s4.y, s4.z, s4.w};
            float ww[4] = {w4.x, w4.y, w4.z, w4.w};
#pragma unroll
            for (int j = 0; j < 4; ++j) {
                if (dd[j] >= N_IN) {
                    int pos = atomicAdd(&lcur[dd[j] >> RB_LOG], 1);
                    staging[pos] = make_int2(((dd[j] & (RB - 1)) << 16) | ss[j],
                                             __float_as_int(ww[j]));
                }
            }
        } else {
            for (int j = 0; j < 4 && e + j < e1; ++j) {
                int d = edge_dst[e + j];
                if (d >= N_IN) {
                    int pos = atomicAdd(&lcur[d >> RB_LOG], 1);
                    staging[pos] = make_int2(((d & (RB - 1)) << 16) | edge_src[e + j],
                                             __float_as_int(weight[e + j]));
                }
            }
        }
    }
}

// ---- K3: per-range fine fill: LDS hist + LDS scan + place edata + offsets ----
__global__ __launch_bounds__(1024)
void k3_kernel(const int2* __restrict__ staging, const int* __restrict__ bases,
               int* __restrict__ offsets, int2* __restrict__ edata, int R) {
    __shared__ int h[RB];
    int tid = threadIdx.x;
    int r = blockIdx.x;
    int b0 = bases[r], b1 = bases[r + 1];
    if (tid < RB) h[tid] = 0;
    __syncthreads();
    for (int i = b0 + tid; i < b1; i += 1024)
        atomicAdd(&h[staging[i].x >> 16], 1);
    __syncthreads();
    int v = (tid < RB) ? h[tid] : 0;
    for (int off = 1; off < RB; off <<= 1) {       // Hillis-Steele inclusive
        int t = (tid < RB && tid >= off) ? h[tid - off] : 0;
        __syncthreads();
        if (tid < RB) h[tid] += t;
        __syncthreads();
    }
    int excl = (tid < RB) ? (h[tid] - v) : 0;
    if (tid < RB) offsets[(size_t)r * RB + tid] = b0 + excl;
    if (r == R - 1 && tid == 0) offsets[(size_t)R * RB] = bases[R];
    __syncthreads();
    if (tid < RB) h[tid] = b0 + excl;              // cursors
    __syncthreads();
    for (int i = b0 + tid; i < b1; i += 1024) {
        int2 st = staging[i];
        int pos = atomicAdd(&h[st.x >> 16], 1);
        edata[pos] = make_int2(st.x & 0xffff, st.y);
    }
}

// ---- K4: agg (wave/node) + tanh + clamp + fused output transpose ----
__global__ __launch_bounds__(1024)
void agg5_kernel(const unsigned short* __restrict__ sTb,
                 const int2* __restrict__ edata,
                 const int* __restrict__ offsets,
                 const float* __restrict__ x,
                 const float* __restrict__ bias,
                 const float* __restrict__ response,
                 float* __restrict__ ns,
                 float* __restrict__ y, int N) {
    __shared__ float tile[16 * 33];
    int n0 = blockIdx.x * 16;
    int wid = threadIdx.x >> 6;       // 0..15 -> node
    int node = n0 + wid;
    int lane = threadIdx.x & 63;
    int q = lane & 15;                // batch pair: b0=2q, b1=2q+1
    int p = lane >> 4;                // edge slot 0..3
    if (node < N) {
        if (node < N_IN) {
            if (p == 0) {
                tile[wid * 33 + 2 * q]     = x[(2 * q) * N_IN + node];
                tile[wid * 33 + 2 * q + 1] = x[(2 * q + 1) * N_IN + node];
            }
        } else {
            int beg = offsets[node];
            int end = offsets[node + 1];
            float a0 = 0.f, a1 = 0.f;
            for (int e = beg + p; e < end; e += 4) {
                int2 ed = edata[e];
                unsigned u = *reinterpret_cast<const unsigned*>(
                    sTb + (size_t)ed.x * 32 + 2 * q);
                float w = __int_as_float(ed.y);
                a0 += w * __uint_as_float(u << 16);
                a1 += w * __uint_as_float(u & 0xffff0000u);
            }
            a0 += __shfl_xor(a0, 16, 64);
            a0 += __shfl_xor(a0, 32, 64);
            a1 += __shfl_xor(a1, 16, 64);
            a1 += __shfl_xor(a1, 32, 64);
            if (p == 0) {
                float bi = bias[node], rs = response[node];
                tile[wid * 33 + 2 * q]     = tanhf(bi + rs * a0);
                tile[wid * 33 + 2 * q + 1] = tanhf(bi + rs * a1);
            }
        }
    }
    __syncthreads();
    if (threadIdx.x < 512) {
        int nl = threadIdx.x & 15;
        int b  = threadIdx.x >> 4;
        int node2 = n0 + nl;
        if (node2 < N) {
            float v = tile[nl * 33 + b];
            ns[(size_t)b * N + node2] = v;
            int k = node2 - (N - N_OUT);
            if (k >= 0) y[b * N_OUT + k] = v;
        }
    }
}

// ---- last-resort fallback (round-1) kernels ----
__global__ void edge_kernel_fb(const float* __restrict__ states,
                               const float* __restrict__ weight,
                               const int* __restrict__ edge_src,
                               const int* __restrict__ edge_dst,
                               float* __restrict__ agg, int E, int N) {
    int e = blockIdx.x * blockDim.x + threadIdx.x;
    if (e >= E) return;
    int s = edge_src[e];
    int d = edge_dst[e];
    float w = weight[e];
#pragma unroll
    for (int b = 0; b < BATCH; ++b)
        atomicAdd(agg + (size_t)b * N + d, w * states[(size_t)b * N + s]);
}

__global__ void finish_kernel_fb(const float* __restrict__ x,
                                 const float* __restrict__ agg,
                                 const float* __restrict__ bias,
                                 const float* __restrict__ response,
                                 float* __restrict__ y, float* __restrict__ ns,
                                 int N) {
    int n = blockIdx.x * blockDim.x + threadIdx.x;
    int b = blockIdx.y;
    if (n >= N) return;
    float v;
    if (n < N_IN) v = x[b * N_IN + n];
    else          v = tanhf(bias[n] + response[n] * agg[(size_t)b * N + n]);
    ns[(size_t)b * N + n] = v;
    int n0 = N - N_OUT;
    if (n >= n0) y[b * N_OUT + (n - n0)] = v;
}

extern "C" void kernel_launch(void* const* d_in, const int* in_sizes, int n_in,
                              void* d_out, int out_size, void* d_ws, size_t ws_size,
                              hipStream_t stream) {
    const float* x        = (const float*)d_in[0];
    const float* states   = (const float*)d_in[1];
    const float* weight   = (const float*)d_in[2];
    const float* bias     = (const float*)d_in[3];
    const float* response = (const float*)d_in[4];
    const int*   edge_src = (const int*)d_in[5];
    const int*   edge_dst = (const int*)d_in[6];

    int N = in_sizes[3];          // 50000
    int E = in_sizes[5];          // 800000

    float* y  = (float*)d_out;                   // (B, N_OUT)
    float* ns = (float*)d_out + BATCH * N_OUT;   // (B, N)

    int tgrid = (N + 31) / 32;                   // 1563
    int R = (N + RB - 1) / RB;                   // 98

    const int HB = 256;                          // coarse-hist blocks
    const int PB = 512;                          // partition blocks
    int hchunk = (((E + HB - 1) / HB) + 3) & ~3;
    int pchunk = (((E + PB - 1) / PB) + 3) & ~3;

    size_t staging_bytes = ((size_t)E * 8 + 15) & ~(size_t)15;
    size_t edata_bytes   = ((size_t)E * 8 + 15) & ~(size_t)15;
    size_t sTb_bytes     = ((size_t)N * 32 * 2 + 15) & ~(size_t)15;
    size_t offs_bytes    = (((size_t)R * RB + 1) * 4 + 15) & ~(size_t)15;
    size_t small_bytes   = (size_t)(MAXR + (MAXR + 1) + MAXR) * 4 + 64;
    size_t needed = staging_bytes + edata_bytes + sTb_bytes + offs_bytes +
                    small_bytes + 64;

    if (ws_size < needed || R > MAXR || N > 65536) {
        // fallback: atomic-scatter path (needs 6.4 MB)
        float* agg = (float*)d_ws;
        hipMemsetAsync(agg, 0, (size_t)BATCH * N * sizeof(float), stream);
        int egrid = (E + 255) / 256;
        edge_kernel_fb<<<egrid, 256, 0, stream>>>(states, weight, edge_src,
                                                  edge_dst, agg, E, N);
        dim3 fgrid((N + 255) / 256, BATCH);
        finish_kernel_fb<<<fgrid, 256, 0, stream>>>(x, agg, bias, response,
                                                    y, ns, N);
        return;
    }

    char* p = (char*)d_ws;
    int2*           staging = (int2*)p;           p += staging_bytes;
    int2*           edata   = (int2*)p;           p += edata_bytes;
    unsigned short* sTb     = (unsigned short*)p; p += sTb_bytes;
    int*            offsets = (int*)p;            p += offs_bytes;
    int*            ccounts = (int*)p;            p += MAXR * 4;
    int*            bases   = (int*)p;            p += (MAXR + 1) * 4;
    int*            cursors = (int*)p;

    hipMemsetAsync(ccounts, 0, MAXR * 4, stream);

    // K0: transpose || coarse hist
    k0_kernel<<<tgrid + HB, 1024, 0, stream>>>(states, sTb, N, tgrid,
                                               edge_dst, ccounts, R, E, hchunk);
    // K1: scan 98 counts -> bases, cursors
    k1_kernel<<<1, MAXR, 0, stream>>>(ccounts, bases, cursors, R);

    // K2: partition into range-grouped staging
    k2_kernel<<<PB, 1024, 0, stream>>>(edge_src, edge_dst, weight,
                                       cursors, staging, E, R, pchunk);

    // K3: per-range fine fill -> edata + offsets
    k3_kernel<<<R, 1024, 0, stream>>>(staging, bases, offsets, edata, R);

    // K4: gather-aggregate + tanh + clamp + fused transpose-out
    int agrid = (N + 15) / 16;
    agg5_kernel<<<agrid, 1024, 0, stream>>>(sTb, edata, offsets, x,
                                            bias, response, ns, y, N);
}